// Round 1
// baseline (2018.880 us; speedup 1.0000x reference)
//
#include <hip/hip_runtime.h>
#include <math.h>

#define B_    16
#define N_    1024
#define G_    16      // blocks per batch
#define ITERS 100

// ws layout: [cnt: B_*ITERS u32, padded to 8192B][gpart: 2*B_*G_*N_ f32][nug: B_*N_ f32]
#define CNT_BYTES   (B_ * ITERS * 4)
#define GPART_OFF   8192
#define GPART_ELEMS (2 * B_ * G_ * N_)
#define NUG_OFF     (GPART_OFF + GPART_ELEMS * 4)

__device__ __forceinline__ float fast_div(float num, float den) {
    float r = __builtin_amdgcn_rcpf(den);
    r = r * (2.0f - den * r);      // one Newton step -> ~full fp32 accuracy
    return num * r;
}

__global__ __launch_bounds__(1024, 4)
void sinkhorn_kernel(const float* __restrict__ C, float* __restrict__ out,
                     float* __restrict__ gpart, float* __restrict__ nug,
                     unsigned int* __restrict__ cnt)
{
    // 64 KB LDS: part[w][j] partial sums; mu vector aliases row 15 (column
    // j of part is only ever read by thread j, so the overwrite is safe).
    __shared__ float part[16 * 1024];
    float* mu_s = &part[15 * 1024];

    const int tid = threadIdx.x;
    const int w   = tid >> 6;        // wave 0..15  -> row group
    const int l   = tid & 63;        // lane        -> column base
    // XCD-affinity swizzle: batch b's 16 blocks share bid%8 (perf heuristic only)
    const int bid = blockIdx.x;
    const int x = bid & 7, s = bid >> 3;
    const int b = x + ((s >> 4) << 3);
    const int g = s & 15;

    const float cons = 1.0f / 1024.0f;

    // ---- load my 4x16 tile of U = exp(-C/eps), rows 64g+4w+rr, cols l+64q ----
    float u[4][16];
    {
        const float* Cb = C + (size_t)b * N_ * N_ + (size_t)(64 * g + 4 * w) * N_ + l;
        #pragma unroll
        for (int rr = 0; rr < 4; ++rr)
            #pragma unroll
            for (int q = 0; q < 16; ++q)
                u[rr][q] = expf(-20.0f * Cb[(size_t)rr * N_ + 64 * q]);
    }

    mu_s[tid] = cons;
    __syncthreads();

    float nu0 = 0.f, nu1 = 0.f, nu2 = 0.f, nu3 = 0.f;

    for (int it = 0; it < ITERS; ++it) {
        // ---- Phase A: s_i = sum_j U_ij * mu_j for my 4 rows ----
        float a0 = 0.f, a1 = 0.f, a2 = 0.f, a3 = 0.f;
        #pragma unroll
        for (int q = 0; q < 16; ++q) {
            float m = mu_s[l + 64 * q];          // conflict-free LDS
            a0 += u[0][q] * m;
            a1 += u[1][q] * m;
            a2 += u[2][q] * m;
            a3 += u[3][q] * m;
        }
        #pragma unroll
        for (int off = 1; off < 64; off <<= 1) {
            a0 += __shfl_xor(a0, off, 64);
            a1 += __shfl_xor(a1, off, 64);
            a2 += __shfl_xor(a2, off, 64);
            a3 += __shfl_xor(a3, off, 64);
        }
        nu0 = fast_div(cons, a0);
        nu1 = fast_div(cons, a1);
        nu2 = fast_div(cons, a2);
        nu3 = fast_div(cons, a3);

        if (it == ITERS - 1 && l < 4) {          // publish final nu chunk
            float nv = nu0;
            if (l == 1) nv = nu1;
            if (l == 2) nv = nu2;
            if (l == 3) nv = nu3;
            nug[b * N_ + 64 * g + 4 * w + l] = nv;
        }

        __syncthreads();   // all phase-A mu reads done before part[15] is clobbered

        // ---- Phase B: per-wave partial p_j = sum_{my 4 rows} U_ij * nu_i ----
        #pragma unroll
        for (int q = 0; q < 16; ++q) {
            float p = u[0][q] * nu0 + u[1][q] * nu1 + u[2][q] * nu2 + u[3][q] * nu3;
            part[w * 1024 + l + 64 * q] = p;     // conflict-free LDS
        }
        __syncthreads();

        // column sums across 16 waves -> this block's partial for column tid
        float ssum = 0.f;
        #pragma unroll
        for (int w2 = 0; w2 < 16; ++w2)
            ssum += part[w2 * 1024 + tid];
        const int buf = it & 1;
        gpart[(((size_t)buf * B_ + b) * G_ + g) * N_ + tid] = ssum;

        // ---- device barrier among the G_ blocks of batch b ----
        __syncthreads();                          // drains each wave's vmcnt
        if (tid == 0) {
            unsigned int* c = &cnt[b * ITERS + it];
            __threadfence();                      // write-back L2 (release)
            __hip_atomic_fetch_add(c, 1u, __ATOMIC_ACQ_REL, __HIP_MEMORY_SCOPE_AGENT);
            while (__hip_atomic_load(c, __ATOMIC_ACQUIRE, __HIP_MEMORY_SCOPE_AGENT) < G_)
                __builtin_amdgcn_s_sleep(2);
            __threadfence();                      // invalidate caches (acquire)
        }
        __syncthreads();

        // ---- reduce the 16 block-partials -> full new mu (redundant per block) ----
        float s2 = 0.f;
        #pragma unroll
        for (int g2 = 0; g2 < 16; ++g2)
            s2 += gpart[(((size_t)buf * B_ + b) * G_ + g2) * N_ + tid];
        mu_s[tid] = fast_div(cons, s2);           // safe: column tid is mine alone
        __syncthreads();
    }

    // ---- epilogue: T_ij = mu_i * U_ij * nu_j ----
    float mu_i[4];
    #pragma unroll
    for (int rr = 0; rr < 4; ++rr)
        mu_i[rr] = mu_s[64 * g + 4 * w + rr];

    float* ob = out + (size_t)b * N_ * N_ + (size_t)(64 * g + 4 * w) * N_ + l;
    const float* nb = nug + b * N_ + l;
    #pragma unroll
    for (int q = 0; q < 16; ++q) {
        float nuv = nb[64 * q];
        #pragma unroll
        for (int rr = 0; rr < 4; ++rr)
            ob[(size_t)rr * N_ + 64 * q] = mu_i[rr] * u[rr][q] * nuv;
    }
}

extern "C" void kernel_launch(void* const* d_in, const int* in_sizes, int n_in,
                              void* d_out, int out_size, void* d_ws, size_t ws_size,
                              hipStream_t stream) {
    const float* C = (const float*)d_in[2];     // (B, N, N); x,y unused
    float* out = (float*)d_out;

    unsigned char* ws = (unsigned char*)d_ws;
    unsigned int* cnt = (unsigned int*)ws;
    float* gpart = (float*)(ws + GPART_OFF);
    float* nug   = (float*)(ws + NUG_OFF);

    hipMemsetAsync(cnt, 0, CNT_BYTES, stream);  // barrier counters must start at 0
    hipLaunchKernelGGL(sinkhorn_kernel, dim3(256), dim3(1024), 0, stream,
                       C, out, gpart, nug, cnt);
}